// Round 6
// baseline (1077.930 us; speedup 1.0000x reference)
//
#include <hip/hip_runtime.h>
#include <stdint.h>
#include <math.h>

typedef unsigned long long u64;

#define CONF_THR   0.005f
#define SCORE_THRf 0.05f
#define IOU_THR    0.45f
#define TOPK       4096
#define MAXDET     100
#define NHIST      8192
#define NIMG       16
#define BCAP       8192
#define CHUNK      512
#define NSLICE     48            // per image: 3 anchors * (12 + 3 + 1) chunks of 512 locs
#define NBLK       (NIMG * NSLICE)

// anchor half-widths/heights per (level, anchor): exact floats
__constant__ float c_half[3][3][2] = {
  {{58.0f, 45.0f}, {78.0f, 99.0f}, {186.5f, 163.0f}},   // stride 32
  {{15.0f, 30.5f}, {31.0f, 22.5f}, {29.5f, 59.5f}},     // stride 16
  {{5.0f, 6.5f},  {8.0f, 15.0f},  {16.5f, 11.5f}},      // stride 8
};

__device__ __forceinline__ float sigmoidf_(float x) {
  return 1.0f / (1.0f + expf(-x));
}

// Decode block -> (image, level, anchor, 512-loc chunk). Thread covers 2 locations.
__device__ __forceinline__ bool slice_decode(const float* __restrict__ p0,
                                             const float* __restrict__ p1,
                                             const float* __restrict__ p2,
                                             int bx, int tid,
                                             int& b, const float*& q, int& HW,
                                             int& nstart, int& a, int& hw0) {
  b = bx / NSLICE;
  int r = bx % NSLICE;
  const float* p; int ch;
  if (r < 36)      { p = p2; HW = 5776; nstart = 5415; a = r / 12;      ch = r % 12; }
  else if (r < 45) { p = p1; HW = 1444; nstart = 1083; a = (r - 36) / 3; ch = (r - 36) % 3; }
  else             { p = p0; HW = 361;  nstart = 0;    a = r - 45;      ch = 0; }
  hw0 = ch * CHUNK + tid * 2;
  if (hw0 >= HW) return false;
  q = p + (size_t)b * 255 * HW;
  return true;
}

// ---------------- K1: per-block private histogram (or atomic-merge fallback) -------
template <bool PRIV>
__global__ void __launch_bounds__(256) k_hist(const float* __restrict__ p0,
                                              const float* __restrict__ p1,
                                              const float* __restrict__ p2,
                                              unsigned* __restrict__ outHist) {
  __shared__ unsigned lh[NHIST];
  for (int i = threadIdx.x; i < NHIST; i += 256) lh[i] = 0;
  __syncthreads();
  int b; const float* q; int HW, nstart, a, hw0;
  bool act = slice_decode(p0, p1, p2, blockIdx.x, threadIdx.x, b, q, HW, nstart, a, hw0);
  if (act) {
    const bool aligned = (HW & 1) == 0;
    const bool e1 = (hw0 + 1 < HW);
    const float* orow = q + (size_t)(a * 85 + 4) * HW + hw0;
    float o0, o1;
    if (aligned) { float2 ov = *(const float2*)orow; o0 = ov.x; o1 = ov.y; }
    else { o0 = orow[0]; o1 = e1 ? orow[1] : -100.0f; }
    float so0 = sigmoidf_(o0), so1 = sigmoidf_(o1);
    bool ov0 = so0 >= CONF_THR;
    bool ov1 = e1 && (so1 >= CONF_THR);
    if (ov0 || ov1) {
      for (int c = 0; c < 80; ++c) {
        const float* crow = q + (size_t)(a * 85 + 5 + c) * HW + hw0;
        float c0, c1;
        if (aligned) { float2 v = *(const float2*)crow; c0 = v.x; c1 = v.y; }
        else { c0 = crow[0]; c1 = e1 ? crow[1] : -100.0f; }
        if (ov0) {
          float cs = sigmoidf_(c0);
          if (cs > SCORE_THRf) atomicAdd(&lh[__float_as_uint(__fmul_rn(cs, so0)) >> 17], 1u);
        }
        if (ov1) {
          float cs = sigmoidf_(c1);
          if (cs > SCORE_THRf) atomicAdd(&lh[__float_as_uint(__fmul_rn(cs, so1)) >> 17], 1u);
        }
      }
    }
  }
  __syncthreads();
  if (PRIV) {
    unsigned* dst = outHist + (size_t)blockIdx.x * NHIST;
    for (int i = threadIdx.x * 4; i < NHIST; i += 1024)
      *(uint4*)(dst + i) = *(const uint4*)(&lh[i]);
  } else {
    unsigned* dst = outHist + (size_t)(blockIdx.x / NSLICE) * NHIST;
    for (int i = threadIdx.x; i < NHIST; i += 256) if (lh[i]) atomicAdd(&dst[i], lh[i]);
  }
}

// ---------------- K1b: merge private histograms -> per-image histogram -------------
__global__ void __launch_bounds__(256) k_merge(const unsigned* __restrict__ priv,
                                               unsigned* __restrict__ merged) {
  const int b = blockIdx.y;
  const int u = blockIdx.x * 256 + threadIdx.x;
  const unsigned* base = priv + (size_t)b * NSLICE * NHIST + u;
  unsigned s = 0;
  #pragma unroll
  for (int sl = 0; sl < NSLICE; ++sl) s += base[(size_t)sl * NHIST];
  merged[(size_t)b * NHIST + u] = s;
}

// ---------------- K2: find boundary bucket -----------------------------------------
__global__ void k_scan(const unsigned* __restrict__ hist, int* __restrict__ bb1) {
  __shared__ unsigned h[NHIST];
  __shared__ unsigned csum[256];
  const int b = blockIdx.x;
  const unsigned* gh = hist + (size_t)b * NHIST;
  for (int i = threadIdx.x; i < NHIST; i += 256) h[i] = gh[i];
  __syncthreads();
  unsigned s = 0;
  for (int j = 0; j < 32; ++j) s += h[threadIdx.x * 32 + j];
  csum[threadIdx.x] = s;
  __syncthreads();
  if (threadIdx.x == 0) {
    unsigned acc = 0; int found = -1;
    for (int c2 = 255; c2 >= 0; --c2) {
      if (acc + csum[c2] >= TOPK) {
        for (int k2 = c2 * 32 + 31; k2 >= c2 * 32; --k2) {
          if (acc + h[k2] >= TOPK) { found = k2; break; }
          acc += h[k2];
        }
        break;
      } else acc += csum[c2];
    }
    bb1[b] = found;  // -1 => fewer than TOPK valid, take all
  }
}

// ---------------- K3: collect winner/boundary keys with cheap logit pre-filter -----
__global__ void __launch_bounds__(256) k_collect(const float* __restrict__ p0,
                                                 const float* __restrict__ p1,
                                                 const float* __restrict__ p2,
                                                 const int* __restrict__ bb1v,
                                                 unsigned* __restrict__ candCount,
                                                 unsigned* __restrict__ bCount,
                                                 u64* __restrict__ candKeys,
                                                 u64* __restrict__ blist) {
  int b; const float* q; int HW, nstart, a, hw0;
  if (!slice_decode(p0, p1, p2, blockIdx.x, threadIdx.x, b, q, HW, nstart, a, hw0)) return;
  const int Bb1 = bb1v[b];
  const float T = (Bb1 > 0) ? __uint_as_float((unsigned)Bb1 << 17) : 0.0f;
  const bool aligned = (HW & 1) == 0;
  const bool e1 = (hw0 + 1 < HW);
  const float* orow = q + (size_t)(a * 85 + 4) * HW + hw0;
  float o0, o1;
  if (aligned) { float2 ov = *(const float2*)orow; o0 = ov.x; o1 = ov.y; }
  else { o0 = orow[0]; o1 = e1 ? orow[1] : -100.0f; }
  float so0 = sigmoidf_(o0), so1 = sigmoidf_(o1);
  bool ov0 = so0 >= CONF_THR;
  bool ov1 = e1 && (so1 >= CONF_THR);
  if (!ov0 && !ov1) return;
  // cheap raw-logit thresholds; conservative (never rejects a true candidate)
  float cth0 = 1e30f, cth1 = 1e30f;
  if (ov0) {
    cth0 = -1e30f;
    if (Bb1 > 0) {
      float u = __fdiv_rn(T, so0);
      cth0 = (u >= 1.0f) ? 15.0f : (logf(__fdiv_rn(u, __fsub_rn(1.0f, u))) - 0.05f);
    }
  }
  if (ov1) {
    cth1 = -1e30f;
    if (Bb1 > 0) {
      float u = __fdiv_rn(T, so1);
      cth1 = (u >= 1.0f) ? 15.0f : (logf(__fdiv_rn(u, __fsub_rn(1.0f, u))) - 0.05f);
    }
  }
  u64* ckg = candKeys + (size_t)b * TOPK;
  u64* blg = blist + (size_t)b * BCAP;
  const int n0 = (nstart + hw0 * 3 + a) * 80;
  const int n1 = n0 + 240;  // next location: +3 anchors * 80
  for (int c = 0; c < 80; ++c) {
    const float* crow = q + (size_t)(a * 85 + 5 + c) * HW + hw0;
    float c0, c1;
    if (aligned) { float2 v = *(const float2*)crow; c0 = v.x; c1 = v.y; }
    else { c0 = crow[0]; c1 = e1 ? crow[1] : -100.0f; }
    #pragma unroll
    for (int k = 0; k < 2; ++k) {
      float cl = k ? c1 : c0;
      if (cl <= (k ? cth1 : cth0)) continue;
      float so = k ? so1 : so0;
      float cs = sigmoidf_(cl);
      if (cs <= SCORE_THRf) continue;
      unsigned bits = __float_as_uint(__fmul_rn(cs, so));
      int bkt = (int)(bits >> 17);
      if (bkt < Bb1) continue;
      unsigned idx = (unsigned)((k ? n1 : n0) + c);
      u64 key = ((u64)(bits ^ 0x80000000u) << 32) | (u64)(0xFFFFFFFFu - idx);
      if (bkt > Bb1) {
        unsigned g = atomicAdd(&candCount[b], 1u); if (g < TOPK) ckg[g] = key;
      } else {
        unsigned g = atomicAdd(&bCount[b], 1u); if (g < BCAP) blg[g] = key;
      }
    }
  }
}

// ---------------- hybrid bitonic sort (descending), 1024 threads -------------------
__device__ __forceinline__ int swz(int i) { return i ^ ((i >> 4) & 0xF); }  // LDS bank swizzle

__device__ __forceinline__ u64 shflx64(u64 x, int m) {
  unsigned lo = __shfl_xor((unsigned)x, m);
  unsigned hi = __shfl_xor((unsigned)(x >> 32), m);
  return ((u64)hi << 32) | lo;
}

template <int V>   // N = 1024*V elements; element i = t*V + v held in r[v]
__device__ void bitonic_hybrid_desc(u64* sb, u64 (&r)[V], int t) {
  const int N = 1024 * V;
  for (int k = 2; k <= N; k <<= 1) {
    for (int j = k >> 1; j > 0; j >>= 1) {
      if (j >= 64 * V) {                       // cross-wave: LDS exchange
        __syncthreads();
        #pragma unroll
        for (int v = 0; v < V; ++v) sb[swz(t * V + v)] = r[v];
        __syncthreads();
        #pragma unroll
        for (int v = 0; v < V; ++v) {
          int i = t * V + v;
          u64 A = r[v], B = sb[swz(i ^ j)];
          bool up = (i & k) == 0, lower = (i & j) == 0;
          r[v] = (up == lower) ? (A > B ? A : B) : (A < B ? A : B);
        }
      } else if (j >= V) {                     // intra-wave: shuffle exchange
        int d = j / V;
        #pragma unroll
        for (int v = 0; v < V; ++v) {
          int i = t * V + v;
          u64 A = r[v], B = shflx64(r[v], d);
          bool up = (i & k) == 0, lower = (i & j) == 0;
          r[v] = (up == lower) ? (A > B ? A : B) : (A < B ? A : B);
        }
      } else {                                 // intra-thread register swap
        #pragma unroll
        for (int v = 0; v < V; ++v) {
          if ((v & j) == 0) {
            int i = t * V + v;
            u64 A = r[v], B = r[v ^ j];
            bool up = (i & k) == 0;
            u64 mx = A > B ? A : B, mn = A > B ? B : A;
            r[v] = up ? mx : mn; r[v ^ j] = up ? mn : mx;
          }
        }
      }
    }
  }
}

// ---------------- K4: fused boundary-sort + final sort + decode + max_coord --------
__global__ void __launch_bounds__(1024) k_sortdecode(
    const unsigned* __restrict__ candCount, const unsigned* __restrict__ bCount,
    u64* __restrict__ candKeys, const u64* __restrict__ blist,
    const float* __restrict__ p0, const float* __restrict__ p1, const float* __restrict__ p2,
    float4* __restrict__ boxS, float* __restrict__ maxcv) {
  __shared__ u64 sb[8192];   // 64 KiB
  const int b = blockIdx.x, t = threadIdx.x;
  unsigned C1 = candCount[b]; if (C1 > TOPK) C1 = TOPK;
  unsigned m = bCount[b];     if (m > BCAP) m = BCAP;
  int need = TOPK - (int)C1;
  int take = need > 0 ? (need < (int)m ? need : (int)m) : 0;
  const u64* bl = blist + (size_t)b * BCAP;
  u64* ck = candKeys + (size_t)b * TOPK;
  if (take > 0) {   // uniform branch
    u64 r8[8];
    #pragma unroll
    for (int v = 0; v < 8; ++v) { int i = t * 8 + v; r8[v] = (i < (int)m) ? bl[i] : 0ull; }
    bitonic_hybrid_desc<8>(sb, r8, t);
    __syncthreads();
    #pragma unroll
    for (int v = 0; v < 8; ++v) sb[swz(t * 8 + v)] = r8[v];
  }
  __syncthreads();
  u64 r4[4];
  #pragma unroll
  for (int v = 0; v < 4; ++v) {
    int i = t * 4 + v;
    u64 key = 0ull;
    if (i < (int)C1) key = ck[i];
    else if (i < (int)C1 + take) key = sb[swz(i - (int)C1)];
    r4[v] = key;
  }
  __syncthreads();   // all reads of sb done before sort<4> rewrites it
  bitonic_hybrid_desc<4>(sb, r4, t);
  float lmax = -INFINITY;
  float4* bs = boxS + (size_t)b * TOPK;
  #pragma unroll
  for (int v = 0; v < 4; ++v) {
    int i = t * 4 + v;
    u64 key = r4[v];
    ck[i] = key;                       // publish sorted order for NMS
    float4 bx = make_float4(0.f, 0.f, 0.f, 0.f);
    float contrib = 0.0f;              // dead rows contribute 0.0 (matches jnp.where)
    if (key != 0ull) {
      unsigned idx = 0xFFFFFFFFu - (unsigned)(key & 0xFFFFFFFFull);
      int n = (int)(idx / 80u);
      const float* p; int HW, W, nstart, L; float fs;
      if (n < 1083)      { p = p0; HW = 361;  W = 19; nstart = 0;    fs = 32.f; L = 0; }
      else if (n < 5415) { p = p1; HW = 1444; W = 38; nstart = 1083; fs = 16.f; L = 1; }
      else               { p = p2; HW = 5776; W = 76; nstart = 5415; fs = 8.f;  L = 2; }
      int r = n - nstart; int hw = r / 3; int an = r % 3;
      int gx = hw % W;    int gy = hw / W;
      const float* qq = p + (size_t)b * 255 * HW + hw;
      float tx = qq[(size_t)(an * 85 + 0) * HW];
      float ty = qq[(size_t)(an * 85 + 1) * HW];
      float tw = qq[(size_t)(an * 85 + 2) * HW];
      float th = qq[(size_t)(an * 85 + 3) * HW];
      float acx = __fadd_rn((float)gx * fs, 0.5f * fs);
      float acy = __fadd_rn((float)gy * fs, 0.5f * fs);
      float sx = sigmoidf_(tx), sy = sigmoidf_(ty);
      float cx = __fadd_rn(acx, __fmul_rn(__fsub_rn(sx, 0.5f), fs));
      float cy = __fadd_rn(acy, __fmul_rn(__fsub_rn(sy, 0.5f), fs));
      float wx = __fmul_rn(c_half[L][an][0], expf(tw));
      float wy = __fmul_rn(c_half[L][an][1], expf(th));
      bx.x = __fsub_rn(cx, wx); bx.y = __fsub_rn(cy, wy);
      bx.z = __fadd_rn(cx, wx); bx.w = __fadd_rn(cy, wy);
      contrib = fmaxf(fmaxf(bx.x, bx.y), fmaxf(bx.z, bx.w));
    }
    bs[i] = bx;
    lmax = fmaxf(lmax, contrib);
  }
  float* red = (float*)(sb + 4096);   // disjoint 4 KiB region
  red[t] = lmax;
  for (int s = 512; s > 0; s >>= 1) {
    __syncthreads();
    if (t < s) red[t] = fmaxf(red[t], red[t + s]);
  }
  __syncthreads();
  if (t == 0) maxcv[b] = red[0];
}

// ---------------- K5: lazy greedy NMS, one wave per image --------------------------
__global__ void __launch_bounds__(64) k_nms(const u64* __restrict__ candKeys,
                                            const float4* __restrict__ boxS,
                                            const float* __restrict__ maxcv,
                                            float* __restrict__ out) {
  const int b = blockIdx.x;
  const int lane = threadIdx.x;
  float* dets = out + (size_t)b * (MAXDET * 5);
  float* lbls = out + (size_t)NIMG * MAXDET * 5 + (size_t)b * MAXDET;
  for (int i = lane; i < MAXDET; i += 64) {
    dets[i * 5 + 0] = 0.f; dets[i * 5 + 1] = 0.f; dets[i * 5 + 2] = 0.f;
    dets[i * 5 + 3] = 0.f; dets[i * 5 + 4] = 0.f;
    lbls[i] = -1.0f;
  }
  const float mc1 = __fadd_rn(maxcv[b], 1.0f);
  const u64* ck = candKeys + (size_t)b * TOPK;
  const float4* bs = boxS + (size_t)b * TOPK;
  float pbx1[2], pby1[2], pbx2[2], pby2[2], parea[2];
  int P = 0;
  bool done = false;
  for (int base = 0; base < TOPK && !done; base += 64) {
    const int e = base + lane;
    u64 key = ck[e];
    float score = -INFINITY; int c = 0;
    float4 bx = bs[e];
    if (key) {
      unsigned mb = (unsigned)(key >> 32);
      score = __uint_as_float(mb ^ 0x80000000u);
      unsigned idx = 0xFFFFFFFFu - (unsigned)(key & 0xFFFFFFFFull);
      c = (int)(idx % 80u);
    }
    float off = __fmul_rn((float)c, mc1);
    float nx1 = __fadd_rn(bx.x, off), ny1 = __fadd_rn(bx.y, off);
    float nx2 = __fadd_rn(bx.z, off), ny2 = __fadd_rn(bx.w, off);
    for (int tt = 0; tt < 64; ++tt) {
      float s_e = __shfl(score, tt);
      if (!(s_e > 0.0f)) { done = true; break; }
      float ex1 = __shfl(nx1, tt), ey1 = __shfl(ny1, tt);
      float ex2 = __shfl(nx2, tt), ey2 = __shfl(ny2, tt);
      float ea = __fmul_rn(__fsub_rn(ex2, ex1), __fsub_rn(ey2, ey1));
      bool sup = false;
      #pragma unroll
      for (int k2 = 0; k2 < 2; ++k2) {
        int pi = k2 * 64 + lane;
        if (pi < P) {
          float tlx = fmaxf(pbx1[k2], ex1), tly = fmaxf(pby1[k2], ey1);
          float brx = fminf(pbx2[k2], ex2), bry = fminf(pby2[k2], ey2);
          float iw = fmaxf(__fsub_rn(brx, tlx), 0.0f);
          float ih = fmaxf(__fsub_rn(bry, tly), 0.0f);
          float inter = __fmul_rn(iw, ih);
          float denom = __fadd_rn(__fsub_rn(__fadd_rn(parea[k2], ea), inter), 1e-12f);
          float iou = __fdiv_rn(inter, denom);
          if (iou > IOU_THR) sup = true;
        }
      }
      if (!__any(sup)) {
        float cx1 = __shfl(bx.x, tt), cy1 = __shfl(bx.y, tt);
        float cx2 = __shfl(bx.z, tt), cy2 = __shfl(bx.w, tt);
        int   ce  = __shfl(c, tt);
        if (lane == (P & 63)) {
          int slot = P >> 6;
          pbx1[slot] = ex1; pby1[slot] = ey1; pbx2[slot] = ex2; pby2[slot] = ey2;
          parea[slot] = ea;
        }
        if (lane == 0) {
          dets[P * 5 + 0] = cx1; dets[P * 5 + 1] = cy1;
          dets[P * 5 + 2] = cx2; dets[P * 5 + 3] = cy2;
          dets[P * 5 + 4] = s_e;
          lbls[P] = (float)ce;
        }
        ++P;
        if (P == MAXDET) { done = true; break; }
      }
    }
  }
}

// ---------------- launch -----------------------------------------------------------
extern "C" void kernel_launch(void* const* d_in, const int* in_sizes, int n_in,
                              void* d_out, int out_size, void* d_ws, size_t ws_size,
                              hipStream_t stream) {
  const float* p0 = (const float*)d_in[0];  // [16,255,19,19]
  const float* p1 = (const float*)d_in[1];  // [16,255,38,38]
  const float* p2 = (const float*)d_in[2];  // [16,255,76,76]
  float* out = (float*)d_out;
  char* ws = (char*)d_ws;

  const size_t OFF_MERGED = 0;                          // 16*8192*4  = 524288
  const size_t OFF_CNT    = 524288;                     // 256 B counters
  const size_t OFF_CK     = 524544;                     // 16*4096*8  = 524288
  const size_t OFF_BL     = 1048832;                    // 16*8192*8  = 1048576
  const size_t OFF_BOX    = 2097408;                    // 16*4096*16 = 1048576
  const size_t OFF_PRIV   = 3145984;                    // 768*8192*4 = 25165824
  const size_t NEED_PRIV  = OFF_PRIV + (size_t)NBLK * NHIST * 4;  // ~28.3 MB

  unsigned* merged = (unsigned*)(ws + OFF_MERGED);
  unsigned* candCount = (unsigned*)(ws + OFF_CNT);
  unsigned* bCount = candCount + 16;
  int* bb1 = (int*)(bCount + 16);
  float* maxcv = (float*)(bb1 + 16);
  u64* candKeys = (u64*)(ws + OFF_CK);
  u64* blist = (u64*)(ws + OFF_BL);
  float4* boxS = (float4*)(ws + OFF_BOX);
  unsigned* priv = (unsigned*)(ws + OFF_PRIV);

  const bool use_priv = ws_size >= NEED_PRIV;
  if (use_priv) {
    hipMemsetAsync(ws + OFF_CNT, 0, 256, stream);
    k_hist<true><<<NBLK, 256, 0, stream>>>(p0, p1, p2, priv);
    k_merge<<<dim3(NHIST / 256, NIMG), 256, 0, stream>>>(priv, merged);
  } else {
    hipMemsetAsync(ws, 0, OFF_CNT + 256, stream);
    k_hist<false><<<NBLK, 256, 0, stream>>>(p0, p1, p2, merged);
  }
  k_scan<<<NIMG, 256, 0, stream>>>(merged, bb1);
  k_collect<<<NBLK, 256, 0, stream>>>(p0, p1, p2, bb1, candCount, bCount, candKeys, blist);
  k_sortdecode<<<NIMG, 1024, 0, stream>>>(candCount, bCount, candKeys, blist,
                                          p0, p1, p2, boxS, maxcv);
  k_nms<<<NIMG, 64, 0, stream>>>(candKeys, boxS, maxcv, out);
}

// Round 7
// 461.209 us; speedup vs baseline: 2.3372x; 2.3372x over previous
//
#include <hip/hip_runtime.h>
#include <stdint.h>
#include <math.h>

typedef unsigned long long u64;

#define CONF_THR   0.005f
#define SCORE_THRf 0.05f
#define IOU_THR    0.45f
#define TOPK       4096
#define MAXDET     100
#define NHIST      8192
#define NIMG       16
#define BCAP       8192
#define NSLICE     27          // per image: 3 anchors * (6 + 2 + 1) chunks of 1024 locs
#define NBLK       (NIMG * NSLICE)
#define LCAP       1024        // per-block LDS emission buffer

// anchor half-widths/heights per (level, anchor): exact floats
__constant__ float c_half[3][3][2] = {
  {{58.0f, 45.0f}, {78.0f, 99.0f}, {186.5f, 163.0f}},   // stride 32
  {{15.0f, 30.5f}, {31.0f, 22.5f}, {29.5f, 59.5f}},     // stride 16
  {{5.0f, 6.5f},  {8.0f, 15.0f},  {16.5f, 11.5f}},      // stride 8
};

__device__ __forceinline__ float sigmoidf_(float x) {
  return 1.0f / (1.0f + expf(-x));
}

// Decode block -> (image, level, anchor, 1024-loc chunk). Thread covers 4 locations.
// PROVEN-FAST structure (round-3 bench: collect <97us): float4 16B/lane loads.
__device__ __forceinline__ bool slice4_decode(const float* __restrict__ p0,
                                              const float* __restrict__ p1,
                                              const float* __restrict__ p2,
                                              int bx, int tid,
                                              int& b, const float*& q, int& HW,
                                              int& nstart, int& a, int& hw0, int& mi) {
  b = bx / NSLICE;
  int r = bx % NSLICE;
  int h0;
  if (r < 18)      { mi = 2; a = r / 6;         h0 = (r % 6) * 1024; }
  else if (r < 24) { mi = 1; a = (r - 18) >> 1; h0 = ((r - 18) & 1) * 1024; }
  else             { mi = 0; a = r - 24;        h0 = 0; }
  const float* p;
  if (mi == 2)      { p = p2; HW = 5776; nstart = 5415; }
  else if (mi == 1) { p = p1; HW = 1444; nstart = 1083; }
  else              { p = p0; HW = 361;  nstart = 0; }
  hw0 = h0 + tid * 4;
  if (hw0 >= HW) return false;
  q = p + (size_t)b * 255 * HW;
  return true;
}

// ---------------- K1: per-block private histogram (or atomic-merge fallback) -------
template <bool PRIV>
__global__ void __launch_bounds__(256) k_hist(const float* __restrict__ p0,
                                              const float* __restrict__ p1,
                                              const float* __restrict__ p2,
                                              unsigned* __restrict__ outHist) {
  __shared__ unsigned lh[NHIST];
  for (int i = threadIdx.x; i < NHIST; i += 256) lh[i] = 0;
  __syncthreads();
  int b; const float* q; int HW, nstart, a, hw0, mi;
  bool act = slice4_decode(p0, p1, p2, blockIdx.x, threadIdx.x, b, q, HW, nstart, a, hw0, mi);
  if (act) {
    const float* orow = q + (size_t)(a * 85 + 4) * HW;
    float so[4]; bool ov[4] = {false, false, false, false};
    if (mi != 0) {                      // HW % 4 == 0 and rows 16B-aligned
      float4 o = *(const float4*)(orow + hw0);
      so[0] = sigmoidf_(o.x); so[1] = sigmoidf_(o.y);
      so[2] = sigmoidf_(o.z); so[3] = sigmoidf_(o.w);
      #pragma unroll
      for (int k = 0; k < 4; ++k) ov[k] = so[k] >= CONF_THR;
    } else {
      #pragma unroll
      for (int k = 0; k < 4; ++k)
        if (hw0 + k < HW) { so[k] = sigmoidf_(orow[hw0 + k]); ov[k] = so[k] >= CONF_THR; }
    }
    for (int c = 0; c < 80; ++c) {
      const float* crow = q + (size_t)(a * 85 + 5 + c) * HW;
      float cv[4];
      if (mi != 0) {
        float4 v = *(const float4*)(crow + hw0);
        cv[0] = v.x; cv[1] = v.y; cv[2] = v.z; cv[3] = v.w;
      } else {
        #pragma unroll
        for (int k = 0; k < 4; ++k) cv[k] = (hw0 + k < HW) ? crow[hw0 + k] : -100.0f;
      }
      #pragma unroll
      for (int k = 0; k < 4; ++k) {
        if (!ov[k]) continue;
        float cs = sigmoidf_(cv[k]);
        if (cs > SCORE_THRf)
          atomicAdd(&lh[__float_as_uint(__fmul_rn(cs, so[k])) >> 17], 1u);
      }
    }
  }
  __syncthreads();
  if (PRIV) {
    unsigned* dst = outHist + (size_t)blockIdx.x * NHIST;
    for (int i = threadIdx.x * 4; i < NHIST; i += 1024)
      *(uint4*)(dst + i) = *(const uint4*)(&lh[i]);
  } else {
    unsigned* dst = outHist + (size_t)(blockIdx.x / NSLICE) * NHIST;
    for (int i = threadIdx.x; i < NHIST; i += 256) if (lh[i]) atomicAdd(&dst[i], lh[i]);
  }
}

// ---------------- K1b: merge private histograms -> per-image histogram -------------
__global__ void __launch_bounds__(256) k_merge(const unsigned* __restrict__ priv,
                                               unsigned* __restrict__ merged) {
  const int b = blockIdx.y;
  const int u = blockIdx.x * 256 + threadIdx.x;
  const unsigned* base = priv + (size_t)b * NSLICE * NHIST + u;
  unsigned s = 0;
  #pragma unroll
  for (int sl = 0; sl < NSLICE; ++sl) s += base[(size_t)sl * NHIST];
  merged[(size_t)b * NHIST + u] = s;
}

// ---------------- K2: find boundary bucket -----------------------------------------
__global__ void k_scan(const unsigned* __restrict__ hist, int* __restrict__ bb1) {
  __shared__ unsigned h[NHIST];
  __shared__ unsigned csum[256];
  const int b = blockIdx.x;
  const unsigned* gh = hist + (size_t)b * NHIST;
  for (int i = threadIdx.x; i < NHIST; i += 256) h[i] = gh[i];
  __syncthreads();
  unsigned s = 0;
  for (int j = 0; j < 32; ++j) s += h[threadIdx.x * 32 + j];
  csum[threadIdx.x] = s;
  __syncthreads();
  if (threadIdx.x == 0) {
    unsigned acc = 0; int found = -1;
    for (int c2 = 255; c2 >= 0; --c2) {
      if (acc + csum[c2] >= TOPK) {
        for (int k2 = c2 * 32 + 31; k2 >= c2 * 32; --k2) {
          if (acc + h[k2] >= TOPK) { found = k2; break; }
          acc += h[k2];
        }
        break;
      } else acc += csum[c2];
    }
    bb1[b] = found;  // -1 => fewer than TOPK valid, take all
  }
}

// ---------------- K3: collect keys; float4 loads + LDS buffers + logit pre-filter ---
__global__ void __launch_bounds__(256) k_collect(const float* __restrict__ p0,
                                                 const float* __restrict__ p1,
                                                 const float* __restrict__ p2,
                                                 const int* __restrict__ bb1v,
                                                 unsigned* __restrict__ candCount,
                                                 unsigned* __restrict__ bCount,
                                                 u64* __restrict__ candKeys,
                                                 u64* __restrict__ blist) {
  __shared__ u64 wbuf[LCAP];
  __shared__ u64 bbuf[LCAP];
  __shared__ unsigned cnt2[2];
  __shared__ unsigned base2[2];
  if (threadIdx.x < 2) cnt2[threadIdx.x] = 0;
  __syncthreads();
  int b; const float* q; int HW, nstart, a, hw0, mi;
  bool act = slice4_decode(p0, p1, p2, blockIdx.x, threadIdx.x, b, q, HW, nstart, a, hw0, mi);
  const int bglobal = blockIdx.x / NSLICE;
  const int Bb1 = bb1v[bglobal];
  u64* ckg = candKeys + (size_t)bglobal * TOPK;
  u64* blg = blist + (size_t)bglobal * BCAP;

  if (act) {
    const float T = (Bb1 > 0) ? __uint_as_float((unsigned)Bb1 << 17) : 0.0f;
    const float* orow = q + (size_t)(a * 85 + 4) * HW;
    float so[4]; bool ov[4] = {false, false, false, false};
    if (mi != 0) {
      float4 o = *(const float4*)(orow + hw0);
      so[0] = sigmoidf_(o.x); so[1] = sigmoidf_(o.y);
      so[2] = sigmoidf_(o.z); so[3] = sigmoidf_(o.w);
      #pragma unroll
      for (int k = 0; k < 4; ++k) ov[k] = so[k] >= CONF_THR;
    } else {
      #pragma unroll
      for (int k = 0; k < 4; ++k)
        if (hw0 + k < HW) { so[k] = sigmoidf_(orow[hw0 + k]); ov[k] = so[k] >= CONF_THR; }
    }
    // cheap raw-logit thresholds; conservative (never rejects a true candidate):
    // cl <= logit(T/so) - 0.05 implies sigmoid(cl)*so < T strictly (margin >> ulp err)
    float cth[4];
    #pragma unroll
    for (int k = 0; k < 4; ++k) {
      cth[k] = 1e30f;
      if (ov[k]) {
        cth[k] = -1e30f;
        if (Bb1 > 0) {
          float u = __fdiv_rn(T, so[k]);
          cth[k] = (u >= 1.0f) ? 15.0f : (logf(__fdiv_rn(u, __fsub_rn(1.0f, u))) - 0.05f);
        }
      }
    }
    for (int c = 0; c < 80; ++c) {
      const float* crow = q + (size_t)(a * 85 + 5 + c) * HW;
      float cv[4];
      if (mi != 0) {
        float4 v = *(const float4*)(crow + hw0);
        cv[0] = v.x; cv[1] = v.y; cv[2] = v.z; cv[3] = v.w;
      } else {
        #pragma unroll
        for (int k = 0; k < 4; ++k) cv[k] = (hw0 + k < HW) ? crow[hw0 + k] : -100.0f;
      }
      #pragma unroll
      for (int k = 0; k < 4; ++k) {
        if (cv[k] <= cth[k]) continue;          // pre-filter: skips sigmoid for 99.8%
        float cs = sigmoidf_(cv[k]);
        if (cs <= SCORE_THRf) continue;
        unsigned bits = __float_as_uint(__fmul_rn(cs, so[k]));
        int bkt = (int)(bits >> 17);
        if (bkt < Bb1) continue;
        unsigned idx = (unsigned)((nstart + (hw0 + k) * 3 + a) * 80 + c);
        u64 key = ((u64)(bits ^ 0x80000000u) << 32) | (u64)(0xFFFFFFFFu - idx);
        if (bkt > Bb1) {
          unsigned pos = atomicAdd(&cnt2[0], 1u);
          if (pos < LCAP) wbuf[pos] = key;
          else { unsigned g = atomicAdd(&candCount[bglobal], 1u); if (g < TOPK) ckg[g] = key; }
        } else {
          unsigned pos = atomicAdd(&cnt2[1], 1u);
          if (pos < LCAP) bbuf[pos] = key;
          else { unsigned g = atomicAdd(&bCount[bglobal], 1u); if (g < BCAP) blg[g] = key; }
        }
      }
    }
  }
  __syncthreads();
  unsigned wn = min(cnt2[0], (unsigned)LCAP);
  unsigned bn = min(cnt2[1], (unsigned)LCAP);
  if (threadIdx.x == 0) base2[0] = wn ? atomicAdd(&candCount[bglobal], wn) : 0u;
  if (threadIdx.x == 1) base2[1] = bn ? atomicAdd(&bCount[bglobal], bn) : 0u;
  __syncthreads();
  for (unsigned i = threadIdx.x; i < wn; i += 256) {
    unsigned g = base2[0] + i; if (g < TOPK) ckg[g] = wbuf[i];
  }
  for (unsigned i = threadIdx.x; i < bn; i += 256) {
    unsigned g = base2[1] + i; if (g < BCAP) blg[g] = bbuf[i];
  }
}

// ---------------- hybrid bitonic sort (descending), 1024 threads -------------------
__device__ __forceinline__ int swz(int i) { return i ^ ((i >> 4) & 0xF); }  // LDS bank swizzle

__device__ __forceinline__ u64 shflx64(u64 x, int m) {
  unsigned lo = __shfl_xor((unsigned)x, m);
  unsigned hi = __shfl_xor((unsigned)(x >> 32), m);
  return ((u64)hi << 32) | lo;
}

template <int V>   // N = 1024*V elements; element i = t*V + v held in r[v]
__device__ void bitonic_hybrid_desc(u64* sb, u64 (&r)[V], int t) {
  const int N = 1024 * V;
  for (int k = 2; k <= N; k <<= 1) {
    for (int j = k >> 1; j > 0; j >>= 1) {
      if (j >= 64 * V) {                       // cross-wave: LDS exchange
        __syncthreads();
        #pragma unroll
        for (int v = 0; v < V; ++v) sb[swz(t * V + v)] = r[v];
        __syncthreads();
        #pragma unroll
        for (int v = 0; v < V; ++v) {
          int i = t * V + v;
          u64 A = r[v], B = sb[swz(i ^ j)];
          bool up = (i & k) == 0, lower = (i & j) == 0;
          r[v] = (up == lower) ? (A > B ? A : B) : (A < B ? A : B);
        }
      } else if (j >= V) {                     // intra-wave: shuffle exchange
        int d = j / V;
        #pragma unroll
        for (int v = 0; v < V; ++v) {
          int i = t * V + v;
          u64 A = r[v], B = shflx64(r[v], d);
          bool up = (i & k) == 0, lower = (i & j) == 0;
          r[v] = (up == lower) ? (A > B ? A : B) : (A < B ? A : B);
        }
      } else {                                 // intra-thread register swap
        #pragma unroll
        for (int v = 0; v < V; ++v) {
          if ((v & j) == 0) {
            int i = t * V + v;
            u64 A = r[v], B = r[v ^ j];
            bool up = (i & k) == 0;
            u64 mx = A > B ? A : B, mn = A > B ? B : A;
            r[v] = up ? mx : mn; r[v ^ j] = up ? mn : mx;
          }
        }
      }
    }
  }
}

// ---------------- K4: fused boundary-sort + final sort + decode + max_coord --------
__global__ void __launch_bounds__(1024) k_sortdecode(
    const unsigned* __restrict__ candCount, const unsigned* __restrict__ bCount,
    u64* __restrict__ candKeys, const u64* __restrict__ blist,
    const float* __restrict__ p0, const float* __restrict__ p1, const float* __restrict__ p2,
    float4* __restrict__ boxS, float* __restrict__ maxcv) {
  __shared__ u64 sb[8192];   // 64 KiB
  const int b = blockIdx.x, t = threadIdx.x;
  unsigned C1 = candCount[b]; if (C1 > TOPK) C1 = TOPK;
  unsigned m = bCount[b];     if (m > BCAP) m = BCAP;
  int need = TOPK - (int)C1;
  int take = need > 0 ? (need < (int)m ? need : (int)m) : 0;
  const u64* bl = blist + (size_t)b * BCAP;
  u64* ck = candKeys + (size_t)b * TOPK;
  if (take > 0) {   // uniform branch
    u64 r8[8];
    #pragma unroll
    for (int v = 0; v < 8; ++v) { int i = t * 8 + v; r8[v] = (i < (int)m) ? bl[i] : 0ull; }
    bitonic_hybrid_desc<8>(sb, r8, t);
    __syncthreads();
    #pragma unroll
    for (int v = 0; v < 8; ++v) sb[swz(t * 8 + v)] = r8[v];
  }
  __syncthreads();
  u64 r4[4];
  #pragma unroll
  for (int v = 0; v < 4; ++v) {
    int i = t * 4 + v;
    u64 key = 0ull;
    if (i < (int)C1) key = ck[i];
    else if (i < (int)C1 + take) key = sb[swz(i - (int)C1)];
    r4[v] = key;
  }
  __syncthreads();   // all reads of sb done before sort<4> rewrites it
  bitonic_hybrid_desc<4>(sb, r4, t);
  float lmax = -INFINITY;
  float4* bs = boxS + (size_t)b * TOPK;
  #pragma unroll
  for (int v = 0; v < 4; ++v) {
    int i = t * 4 + v;
    u64 key = r4[v];
    ck[i] = key;                       // publish sorted order for NMS
    float4 bx = make_float4(0.f, 0.f, 0.f, 0.f);
    float contrib = 0.0f;              // dead rows contribute 0.0 (matches jnp.where)
    if (key != 0ull) {
      unsigned idx = 0xFFFFFFFFu - (unsigned)(key & 0xFFFFFFFFull);
      int n = (int)(idx / 80u);
      const float* p; int HW, W, nstart, L; float fs;
      if (n < 1083)      { p = p0; HW = 361;  W = 19; nstart = 0;    fs = 32.f; L = 0; }
      else if (n < 5415) { p = p1; HW = 1444; W = 38; nstart = 1083; fs = 16.f; L = 1; }
      else               { p = p2; HW = 5776; W = 76; nstart = 5415; fs = 8.f;  L = 2; }
      int r = n - nstart; int hw = r / 3; int an = r % 3;
      int gx = hw % W;    int gy = hw / W;
      const float* qq = p + (size_t)b * 255 * HW + hw;
      float tx = qq[(size_t)(an * 85 + 0) * HW];
      float ty = qq[(size_t)(an * 85 + 1) * HW];
      float tw = qq[(size_t)(an * 85 + 2) * HW];
      float th = qq[(size_t)(an * 85 + 3) * HW];
      float acx = __fadd_rn((float)gx * fs, 0.5f * fs);
      float acy = __fadd_rn((float)gy * fs, 0.5f * fs);
      float sx = sigmoidf_(tx), sy = sigmoidf_(ty);
      float cx = __fadd_rn(acx, __fmul_rn(__fsub_rn(sx, 0.5f), fs));
      float cy = __fadd_rn(acy, __fmul_rn(__fsub_rn(sy, 0.5f), fs));
      float wx = __fmul_rn(c_half[L][an][0], expf(tw));
      float wy = __fmul_rn(c_half[L][an][1], expf(th));
      bx.x = __fsub_rn(cx, wx); bx.y = __fsub_rn(cy, wy);
      bx.z = __fadd_rn(cx, wx); bx.w = __fadd_rn(cy, wy);
      contrib = fmaxf(fmaxf(bx.x, bx.y), fmaxf(bx.z, bx.w));
    }
    bs[i] = bx;
    lmax = fmaxf(lmax, contrib);
  }
  float* red = (float*)(sb + 4096);   // disjoint 4 KiB region
  red[t] = lmax;
  for (int s = 512; s > 0; s >>= 1) {
    __syncthreads();
    if (t < s) red[t] = fmaxf(red[t], red[t + s]);
  }
  __syncthreads();
  if (t == 0) maxcv[b] = red[0];
}

// ---------------- K5: lazy greedy NMS, one wave per image --------------------------
__global__ void __launch_bounds__(64) k_nms(const u64* __restrict__ candKeys,
                                            const float4* __restrict__ boxS,
                                            const float* __restrict__ maxcv,
                                            float* __restrict__ out) {
  const int b = blockIdx.x;
  const int lane = threadIdx.x;
  float* dets = out + (size_t)b * (MAXDET * 5);
  float* lbls = out + (size_t)NIMG * MAXDET * 5 + (size_t)b * MAXDET;
  for (int i = lane; i < MAXDET; i += 64) {
    dets[i * 5 + 0] = 0.f; dets[i * 5 + 1] = 0.f; dets[i * 5 + 2] = 0.f;
    dets[i * 5 + 3] = 0.f; dets[i * 5 + 4] = 0.f;
    lbls[i] = -1.0f;
  }
  const float mc1 = __fadd_rn(maxcv[b], 1.0f);
  const u64* ck = candKeys + (size_t)b * TOPK;
  const float4* bs = boxS + (size_t)b * TOPK;
  float pbx1[2], pby1[2], pbx2[2], pby2[2], parea[2];
  int P = 0;
  bool done = false;
  for (int base = 0; base < TOPK && !done; base += 64) {
    const int e = base + lane;
    u64 key = ck[e];
    float score = -INFINITY; int c = 0;
    float4 bx = bs[e];
    if (key) {
      unsigned mb = (unsigned)(key >> 32);
      score = __uint_as_float(mb ^ 0x80000000u);
      unsigned idx = 0xFFFFFFFFu - (unsigned)(key & 0xFFFFFFFFull);
      c = (int)(idx % 80u);
    }
    float off = __fmul_rn((float)c, mc1);
    float nx1 = __fadd_rn(bx.x, off), ny1 = __fadd_rn(bx.y, off);
    float nx2 = __fadd_rn(bx.z, off), ny2 = __fadd_rn(bx.w, off);
    for (int tt = 0; tt < 64; ++tt) {
      float s_e = __shfl(score, tt);
      if (!(s_e > 0.0f)) { done = true; break; }
      float ex1 = __shfl(nx1, tt), ey1 = __shfl(ny1, tt);
      float ex2 = __shfl(nx2, tt), ey2 = __shfl(ny2, tt);
      float ea = __fmul_rn(__fsub_rn(ex2, ex1), __fsub_rn(ey2, ey1));
      bool sup = false;
      #pragma unroll
      for (int k2 = 0; k2 < 2; ++k2) {
        int pi = k2 * 64 + lane;
        if (pi < P) {
          float tlx = fmaxf(pbx1[k2], ex1), tly = fmaxf(pby1[k2], ey1);
          float brx = fminf(pbx2[k2], ex2), bry = fminf(pby2[k2], ey2);
          float iw = fmaxf(__fsub_rn(brx, tlx), 0.0f);
          float ih = fmaxf(__fsub_rn(bry, tly), 0.0f);
          float inter = __fmul_rn(iw, ih);
          float denom = __fadd_rn(__fsub_rn(__fadd_rn(parea[k2], ea), inter), 1e-12f);
          float iou = __fdiv_rn(inter, denom);
          if (iou > IOU_THR) sup = true;
        }
      }
      if (!__any(sup)) {
        float cx1 = __shfl(bx.x, tt), cy1 = __shfl(bx.y, tt);
        float cx2 = __shfl(bx.z, tt), cy2 = __shfl(bx.w, tt);
        int   ce  = __shfl(c, tt);
        if (lane == (P & 63)) {
          int slot = P >> 6;
          pbx1[slot] = ex1; pby1[slot] = ey1; pbx2[slot] = ex2; pby2[slot] = ey2;
          parea[slot] = ea;
        }
        if (lane == 0) {
          dets[P * 5 + 0] = cx1; dets[P * 5 + 1] = cy1;
          dets[P * 5 + 2] = cx2; dets[P * 5 + 3] = cy2;
          dets[P * 5 + 4] = s_e;
          lbls[P] = (float)ce;
        }
        ++P;
        if (P == MAXDET) { done = true; break; }
      }
    }
  }
}

// ---------------- launch -----------------------------------------------------------
extern "C" void kernel_launch(void* const* d_in, const int* in_sizes, int n_in,
                              void* d_out, int out_size, void* d_ws, size_t ws_size,
                              hipStream_t stream) {
  const float* p0 = (const float*)d_in[0];  // [16,255,19,19]
  const float* p1 = (const float*)d_in[1];  // [16,255,38,38]
  const float* p2 = (const float*)d_in[2];  // [16,255,76,76]
  float* out = (float*)d_out;
  char* ws = (char*)d_ws;

  const size_t OFF_MERGED = 0;                          // 16*8192*4  = 524288
  const size_t OFF_CNT    = 524288;                     // 256 B counters
  const size_t OFF_CK     = 524544;                     // 16*4096*8  = 524288
  const size_t OFF_BL     = 1048832;                    // 16*8192*8  = 1048576
  const size_t OFF_BOX    = 2097408;                    // 16*4096*16 = 1048576
  const size_t OFF_PRIV   = 3145984;                    // 432*8192*4 = 14155776
  const size_t NEED_PRIV  = OFF_PRIV + (size_t)NBLK * NHIST * 4;  // 17301760

  unsigned* merged = (unsigned*)(ws + OFF_MERGED);
  unsigned* candCount = (unsigned*)(ws + OFF_CNT);
  unsigned* bCount = candCount + 16;
  int* bb1 = (int*)(bCount + 16);
  float* maxcv = (float*)(bb1 + 16);
  u64* candKeys = (u64*)(ws + OFF_CK);
  u64* blist = (u64*)(ws + OFF_BL);
  float4* boxS = (float4*)(ws + OFF_BOX);
  unsigned* priv = (unsigned*)(ws + OFF_PRIV);

  const bool use_priv = ws_size >= NEED_PRIV;
  if (use_priv) {
    hipMemsetAsync(ws + OFF_CNT, 0, 256, stream);
    k_hist<true><<<NBLK, 256, 0, stream>>>(p0, p1, p2, priv);
    k_merge<<<dim3(NHIST / 256, NIMG), 256, 0, stream>>>(priv, merged);
  } else {
    hipMemsetAsync(ws, 0, OFF_CNT + 256, stream);
    k_hist<false><<<NBLK, 256, 0, stream>>>(p0, p1, p2, merged);
  }
  k_scan<<<NIMG, 256, 0, stream>>>(merged, bb1);
  k_collect<<<NBLK, 256, 0, stream>>>(p0, p1, p2, bb1, candCount, bCount, candKeys, blist);
  k_sortdecode<<<NIMG, 1024, 0, stream>>>(candCount, bCount, candKeys, blist,
                                          p0, p1, p2, boxS, maxcv);
  k_nms<<<NIMG, 64, 0, stream>>>(candKeys, boxS, maxcv, out);
}

// Round 9
// 396.148 us; speedup vs baseline: 2.7210x; 1.1642x over previous
//
#include <hip/hip_runtime.h>
#include <stdint.h>
#include <math.h>

typedef unsigned long long u64;

#define CONF_THR   0.005f
#define SCORE_THRf 0.05f
#define IOU_THR    0.45f
#define TOPK       4096
#define MAXDET     100
#define NHIST      8192
#define NIMG       16
#define BCAP       8192
#define LCAP       1024
// collect slicing (proven round-7): 27 slices of 1024 locs, 256 thr x 4 locs
#define NSLICE_C   27
#define NBLK_C     (NIMG * NSLICE_C)
// hist slicing: 48 slices of 512 locs, 128 thr x 4 locs
#define NSLICE_H   48
#define NBLK_H     (NIMG * NSLICE_H)

// anchor half-widths/heights per (level, anchor): exact floats
__constant__ float c_half[3][3][2] = {
  {{58.0f, 45.0f}, {78.0f, 99.0f}, {186.5f, 163.0f}},   // stride 32
  {{15.0f, 30.5f}, {31.0f, 22.5f}, {29.5f, 59.5f}},     // stride 16
  {{5.0f, 6.5f},  {8.0f, 15.0f},  {16.5f, 11.5f}},      // stride 8
};

__device__ __forceinline__ float sigmoidf_(float x) {
  return 1.0f / (1.0f + expf(-x));
}

// ---- decode for collect: 1024-loc chunks, 256 threads x 4 locs (float4) ----------
__device__ __forceinline__ bool slice_c(const float* __restrict__ p0,
                                        const float* __restrict__ p1,
                                        const float* __restrict__ p2,
                                        int bx, int tid,
                                        int& b, const float*& q, int& HW,
                                        int& nstart, int& a, int& hw0, int& mi) {
  b = bx / NSLICE_C;
  int r = bx % NSLICE_C;
  int h0;
  if (r < 18)      { mi = 2; a = r / 6;         h0 = (r % 6) * 1024; }
  else if (r < 24) { mi = 1; a = (r - 18) >> 1; h0 = ((r - 18) & 1) * 1024; }
  else             { mi = 0; a = r - 24;        h0 = 0; }
  const float* p;
  if (mi == 2)      { p = p2; HW = 5776; nstart = 5415; }
  else if (mi == 1) { p = p1; HW = 1444; nstart = 1083; }
  else              { p = p0; HW = 361;  nstart = 0; }
  hw0 = h0 + tid * 4;
  if (hw0 >= HW) return false;
  q = p + (size_t)b * 255 * HW;
  return true;
}

// ---- decode for hist: 512-loc chunks, 128 threads x 4 locs (float4) --------------
__device__ __forceinline__ bool slice_h(const float* __restrict__ p0,
                                        const float* __restrict__ p1,
                                        const float* __restrict__ p2,
                                        int bx, int tid,
                                        int& b, const float*& q, int& HW,
                                        int& a, int& hw0, int& mi) {
  b = bx / NSLICE_H;
  int r = bx % NSLICE_H;
  int ch;
  if (r < 36)      { mi = 2; a = r / 12;       ch = r % 12; }
  else if (r < 45) { mi = 1; a = (r - 36) / 3; ch = (r - 36) % 3; }
  else             { mi = 0; a = r - 45;       ch = 0; }
  const float* p;
  if (mi == 2)      { p = p2; HW = 5776; }
  else if (mi == 1) { p = p1; HW = 1444; }
  else              { p = p0; HW = 361; }
  hw0 = ch * 512 + tid * 4;
  if (hw0 >= HW) return false;
  q = p + (size_t)b * 255 * HW;
  return true;
}

// ---------------- K1: per-block private histogram (or atomic-merge fallback) -------
template <bool PRIV>
__global__ void __launch_bounds__(128) k_hist(const float* __restrict__ p0,
                                              const float* __restrict__ p1,
                                              const float* __restrict__ p2,
                                              unsigned* __restrict__ outHist) {
  __shared__ unsigned lh[NHIST];
  for (int i = threadIdx.x; i < NHIST; i += 128) lh[i] = 0;
  __syncthreads();
  int b; const float* q; int HW, a, hw0, mi;
  bool act = slice_h(p0, p1, p2, blockIdx.x, threadIdx.x, b, q, HW, a, hw0, mi);
  if (act) {
    const float* orow = q + (size_t)(a * 85 + 4) * HW;
    float so[4]; bool ov[4] = {false, false, false, false};
    if (mi != 0) {                      // HW % 4 == 0: full float4 safe
      float4 o = *(const float4*)(orow + hw0);
      so[0] = sigmoidf_(o.x); so[1] = sigmoidf_(o.y);
      so[2] = sigmoidf_(o.z); so[3] = sigmoidf_(o.w);
      #pragma unroll
      for (int k = 0; k < 4; ++k) ov[k] = so[k] >= CONF_THR;
    } else {
      #pragma unroll
      for (int k = 0; k < 4; ++k)
        if (hw0 + k < HW) { so[k] = sigmoidf_(orow[hw0 + k]); ov[k] = so[k] >= CONF_THR; }
    }
    for (int c = 0; c < 80; ++c) {
      const float* crow = q + (size_t)(a * 85 + 5 + c) * HW;
      float cv[4];
      if (mi != 0) {
        float4 v = *(const float4*)(crow + hw0);
        cv[0] = v.x; cv[1] = v.y; cv[2] = v.z; cv[3] = v.w;
      } else {
        #pragma unroll
        for (int k = 0; k < 4; ++k) cv[k] = (hw0 + k < HW) ? crow[hw0 + k] : -100.0f;
      }
      #pragma unroll
      for (int k = 0; k < 4; ++k) {
        if (!ov[k]) continue;
        float cs = sigmoidf_(cv[k]);
        if (cs > SCORE_THRf)
          atomicAdd(&lh[__float_as_uint(__fmul_rn(cs, so[k])) >> 17], 1u);
      }
    }
  }
  __syncthreads();
  if (PRIV) {
    unsigned* dst = outHist + (size_t)blockIdx.x * NHIST;
    for (int i = threadIdx.x * 4; i < NHIST; i += 512)
      *(uint4*)(dst + i) = *(const uint4*)(&lh[i]);
  } else {
    unsigned* dst = outHist + (size_t)(blockIdx.x / NSLICE_H) * NHIST;
    for (int i = threadIdx.x; i < NHIST; i += 128) if (lh[i]) atomicAdd(&dst[i], lh[i]);
  }
}

// ---------------- K1b: merge private histograms -> per-image histogram -------------
__global__ void __launch_bounds__(256) k_merge(const unsigned* __restrict__ priv,
                                               unsigned* __restrict__ merged) {
  const int b = blockIdx.y;
  const int u = blockIdx.x * 256 + threadIdx.x;
  const unsigned* base = priv + (size_t)b * NSLICE_H * NHIST + u;
  unsigned s = 0;
  #pragma unroll
  for (int sl = 0; sl < NSLICE_H; ++sl) s += base[(size_t)sl * NHIST];
  merged[(size_t)b * NHIST + u] = s;
}

// ---------------- K2: find boundary bucket -----------------------------------------
__global__ void k_scan(const unsigned* __restrict__ hist, int* __restrict__ bb1) {
  __shared__ unsigned h[NHIST];
  __shared__ unsigned csum[256];
  const int b = blockIdx.x;
  const unsigned* gh = hist + (size_t)b * NHIST;
  for (int i = threadIdx.x; i < NHIST; i += 256) h[i] = gh[i];
  __syncthreads();
  unsigned s = 0;
  for (int j = 0; j < 32; ++j) s += h[threadIdx.x * 32 + j];
  csum[threadIdx.x] = s;
  __syncthreads();
  if (threadIdx.x == 0) {
    unsigned acc = 0; int found = -1;
    for (int c2 = 255; c2 >= 0; --c2) {
      if (acc + csum[c2] >= TOPK) {
        for (int k2 = c2 * 32 + 31; k2 >= c2 * 32; --k2) {
          if (acc + h[k2] >= TOPK) { found = k2; break; }
          acc += h[k2];
        }
        break;
      } else acc += csum[c2];
    }
    bb1[b] = found;  // -1 => fewer than TOPK valid, take all
  }
}

// ---------------- K3: collect keys; float4 loads + LDS buffers + logit pre-filter ---
__global__ void __launch_bounds__(256) k_collect(const float* __restrict__ p0,
                                                 const float* __restrict__ p1,
                                                 const float* __restrict__ p2,
                                                 const int* __restrict__ bb1v,
                                                 unsigned* __restrict__ candCount,
                                                 unsigned* __restrict__ bCount,
                                                 u64* __restrict__ candKeys,
                                                 u64* __restrict__ blist) {
  __shared__ u64 wbuf[LCAP];
  __shared__ u64 bbuf[LCAP];
  __shared__ unsigned cnt2[2];
  __shared__ unsigned base2[2];
  if (threadIdx.x < 2) cnt2[threadIdx.x] = 0;
  __syncthreads();
  int b; const float* q; int HW, nstart, a, hw0, mi;
  bool act = slice_c(p0, p1, p2, blockIdx.x, threadIdx.x, b, q, HW, nstart, a, hw0, mi);
  const int bglobal = blockIdx.x / NSLICE_C;
  const int Bb1 = bb1v[bglobal];
  u64* ckg = candKeys + (size_t)bglobal * TOPK;
  u64* blg = blist + (size_t)bglobal * BCAP;

  if (act) {
    const float T = (Bb1 > 0) ? __uint_as_float((unsigned)Bb1 << 17) : 0.0f;
    const float* orow = q + (size_t)(a * 85 + 4) * HW;
    float so[4]; bool ov[4] = {false, false, false, false};
    if (mi != 0) {
      float4 o = *(const float4*)(orow + hw0);
      so[0] = sigmoidf_(o.x); so[1] = sigmoidf_(o.y);
      so[2] = sigmoidf_(o.z); so[3] = sigmoidf_(o.w);
      #pragma unroll
      for (int k = 0; k < 4; ++k) ov[k] = so[k] >= CONF_THR;
    } else {
      #pragma unroll
      for (int k = 0; k < 4; ++k)
        if (hw0 + k < HW) { so[k] = sigmoidf_(orow[hw0 + k]); ov[k] = so[k] >= CONF_THR; }
    }
    // cheap raw-logit thresholds; conservative (never rejects a true candidate):
    // cl <= logit(T/so) - 0.05 implies sigmoid(cl)*so < T strictly (margin >> ulp err)
    float cth[4];
    #pragma unroll
    for (int k = 0; k < 4; ++k) {
      cth[k] = 1e30f;
      if (ov[k]) {
        cth[k] = -1e30f;
        if (Bb1 > 0) {
          float u = __fdiv_rn(T, so[k]);
          cth[k] = (u >= 1.0f) ? 15.0f : (logf(__fdiv_rn(u, __fsub_rn(1.0f, u))) - 0.05f);
        }
      }
    }
    for (int c = 0; c < 80; ++c) {
      const float* crow = q + (size_t)(a * 85 + 5 + c) * HW;
      float cv[4];
      if (mi != 0) {
        float4 v = *(const float4*)(crow + hw0);
        cv[0] = v.x; cv[1] = v.y; cv[2] = v.z; cv[3] = v.w;
      } else {
        #pragma unroll
        for (int k = 0; k < 4; ++k) cv[k] = (hw0 + k < HW) ? crow[hw0 + k] : -100.0f;
      }
      #pragma unroll
      for (int k = 0; k < 4; ++k) {
        if (cv[k] <= cth[k]) continue;          // pre-filter: skips sigmoid for ~99.8%
        float cs = sigmoidf_(cv[k]);
        if (cs <= SCORE_THRf) continue;
        unsigned bits = __float_as_uint(__fmul_rn(cs, so[k]));
        int bkt = (int)(bits >> 17);
        if (bkt < Bb1) continue;
        unsigned idx = (unsigned)((nstart + (hw0 + k) * 3 + a) * 80 + c);
        u64 key = ((u64)(bits ^ 0x80000000u) << 32) | (u64)(0xFFFFFFFFu - idx);
        if (bkt > Bb1) {
          unsigned pos = atomicAdd(&cnt2[0], 1u);
          if (pos < LCAP) wbuf[pos] = key;
          else { unsigned g = atomicAdd(&candCount[bglobal], 1u); if (g < TOPK) ckg[g] = key; }
        } else {
          unsigned pos = atomicAdd(&cnt2[1], 1u);
          if (pos < LCAP) bbuf[pos] = key;
          else { unsigned g = atomicAdd(&bCount[bglobal], 1u); if (g < BCAP) blg[g] = key; }
        }
      }
    }
  }
  __syncthreads();
  unsigned wn = min(cnt2[0], (unsigned)LCAP);
  unsigned bn = min(cnt2[1], (unsigned)LCAP);
  if (threadIdx.x == 0) base2[0] = wn ? atomicAdd(&candCount[bglobal], wn) : 0u;
  if (threadIdx.x == 1) base2[1] = bn ? atomicAdd(&bCount[bglobal], bn) : 0u;
  __syncthreads();
  for (unsigned i = threadIdx.x; i < wn; i += 256) {
    unsigned g = base2[0] + i; if (g < TOPK) ckg[g] = wbuf[i];
  }
  for (unsigned i = threadIdx.x; i < bn; i += 256) {
    unsigned g = base2[1] + i; if (g < BCAP) blg[g] = bbuf[i];
  }
}

// ---------------- bitonic machinery -------------------------------------------------
__device__ __forceinline__ int swz(int i) { return i ^ ((i >> 4) & 0xF); }

__device__ __forceinline__ u64 shflx64(u64 x, int m) {
  unsigned lo = __shfl_xor((unsigned)x, m);
  unsigned hi = __shfl_xor((unsigned)(x >> 32), m);
  return ((u64)hi << 32) | lo;
}

// Generic LDS bitonic (descending), runtime p2, any nthr; barrier after each stage.
__device__ void bitonic_lds_desc(u64* sb, int p2, int nthr, int t) {
  for (int k = 2; k <= p2; k <<= 1) {
    for (int j = k >> 1; j > 0; j >>= 1) {
      for (int i = t; i < p2; i += nthr) {
        int ixj = i ^ j;
        if (ixj > i) {
          u64 A = sb[swz(i)], B = sb[swz(ixj)];
          bool up = (i & k) == 0;
          if (up ? (A < B) : (A > B)) { sb[swz(i)] = B; sb[swz(ixj)] = A; }
        }
      }
      __syncthreads();
    }
  }
}

// Register-held stage-range executor: element i = t*V + v (local), direction uses
// global index i+iofs. Runs network stages k = kFrom..kTo (descending overall sort).
template <int V, int NTHR>
__device__ void bitonic_stages(u64* sb, u64 (&r)[V], int t, int kFrom, int kTo, int iofs) {
  for (int k = kFrom; k <= kTo; k <<= 1) {
    for (int j = k >> 1; j > 0; j >>= 1) {
      if (j >= 64 * V) {                       // cross-wave: LDS exchange
        __syncthreads();
        #pragma unroll
        for (int v = 0; v < V; ++v) sb[swz(t * V + v)] = r[v];
        __syncthreads();
        #pragma unroll
        for (int v = 0; v < V; ++v) {
          int i = t * V + v;
          u64 A = r[v], B = sb[swz(i ^ j)];
          bool up = ((i + iofs) & k) == 0, lower = (i & j) == 0;
          r[v] = (up == lower) ? (A > B ? A : B) : (A < B ? A : B);
        }
      } else if (j >= V) {                     // intra-wave: shuffle exchange
        int d = j / V;
        #pragma unroll
        for (int v = 0; v < V; ++v) {
          int i = t * V + v;
          u64 A = r[v], B = shflx64(r[v], d);
          bool up = ((i + iofs) & k) == 0, lower = (i & j) == 0;
          r[v] = (up == lower) ? (A > B ? A : B) : (A < B ? A : B);
        }
      } else {                                 // intra-thread register swap
        #pragma unroll
        for (int v = 0; v < V; ++v) {
          if ((v & j) == 0) {
            int i = t * V + v;
            u64 A = r[v], B = r[v ^ j];
            bool up = ((i + iofs) & k) == 0;
            u64 mx = A > B ? A : B, mn = A > B ? B : A;
            r[v] = up ? mx : mn; r[v ^ j] = up ? mn : mx;
          }
        }
      }
    }
  }
}

// ---------------- K4a: adaptive boundary select -> fill candKeys to exactly 4096 ---
__global__ void __launch_bounds__(1024) k_bsel(const unsigned* __restrict__ candCount,
                                               const unsigned* __restrict__ bCount,
                                               u64* __restrict__ candKeys,
                                               const u64* __restrict__ blist) {
  __shared__ u64 sb[BCAP];   // 64 KiB
  const int b = blockIdx.x, t = threadIdx.x;
  unsigned C1 = candCount[b]; if (C1 > TOPK) C1 = TOPK;
  unsigned m = bCount[b];     if (m > BCAP) m = BCAP;
  int need = TOPK - (int)C1;
  int take = need > 0 ? (need < (int)m ? need : (int)m) : 0;
  u64* ck = candKeys + (size_t)b * TOPK;
  const u64* bl = blist + (size_t)b * BCAP;
  if (take > 0) {                       // uniform branch (counters are block-uniform)
    int p2 = 1; while (p2 < (int)m) p2 <<= 1;
    for (int i = t; i < p2; i += 1024) sb[swz(i)] = (i < (int)m) ? bl[i] : 0ull;
    __syncthreads();
    bitonic_lds_desc(sb, p2, 1024, t);  // ends with barrier
    for (int i = t; i < take; i += 1024) ck[C1 + i] = sb[swz(i)];
  }
  for (int i = (int)C1 + take + t; i < TOPK; i += 1024) ck[i] = 0ull;
}

// ---------------- K4b: chunk sort — network stages k=2..1024 within 1024-chunks ----
__global__ void __launch_bounds__(256) k_chunksort(u64* __restrict__ candKeys) {
  __shared__ u64 sb[1024];   // 8 KiB
  const int img = blockIdx.x >> 2, c = blockIdx.x & 3, t = threadIdx.x;
  u64* ck = candKeys + (size_t)img * TOPK + c * 1024;
  u64 r[4];
  #pragma unroll
  for (int v = 0; v < 4; ++v) r[v] = ck[t * 4 + v];
  bitonic_stages<4, 256>(sb, r, t, 2, 1024, c * 1024);
  #pragma unroll
  for (int v = 0; v < 4; ++v) ck[t * 4 + v] = r[v];
}

// ---------------- K4c: final merge stages k=2048,4096 + decode + max_coord ---------
__global__ void __launch_bounds__(1024) k_mergedecode(
    u64* __restrict__ candKeys,
    const float* __restrict__ p0, const float* __restrict__ p1, const float* __restrict__ p2,
    float4* __restrict__ boxS, float* __restrict__ maxcv) {
  __shared__ u64 sb[TOPK];      // 32 KiB
  __shared__ float red[1024];   // 4 KiB
  const int b = blockIdx.x, t = threadIdx.x;
  u64* ck = candKeys + (size_t)b * TOPK;
  u64 r[4];
  #pragma unroll
  for (int v = 0; v < 4; ++v) r[v] = ck[t * 4 + v];
  bitonic_stages<4, 1024>(sb, r, t, 2048, 4096, 0);
  float lmax = -INFINITY;
  float4* bs = boxS + (size_t)b * TOPK;
  #pragma unroll
  for (int v = 0; v < 4; ++v) {
    int i = t * 4 + v;
    u64 key = r[v];
    ck[i] = key;                       // publish sorted order for NMS
    float4 bx = make_float4(0.f, 0.f, 0.f, 0.f);
    float contrib = 0.0f;              // dead rows contribute 0.0 (matches jnp.where)
    if (key != 0ull) {
      unsigned idx = 0xFFFFFFFFu - (unsigned)(key & 0xFFFFFFFFull);
      int n = (int)(idx / 80u);
      const float* p; int HW, W, nstart, L; float fs;
      if (n < 1083)      { p = p0; HW = 361;  W = 19; nstart = 0;    fs = 32.f; L = 0; }
      else if (n < 5415) { p = p1; HW = 1444; W = 38; nstart = 1083; fs = 16.f; L = 1; }
      else               { p = p2; HW = 5776; W = 76; nstart = 5415; fs = 8.f;  L = 2; }
      int rr = n - nstart; int hw = rr / 3; int an = rr % 3;
      int gx = hw % W;     int gy = hw / W;
      const float* qq = p + (size_t)b * 255 * HW + hw;
      float tx = qq[(size_t)(an * 85 + 0) * HW];
      float ty = qq[(size_t)(an * 85 + 1) * HW];
      float tw = qq[(size_t)(an * 85 + 2) * HW];
      float th = qq[(size_t)(an * 85 + 3) * HW];
      float acx = __fadd_rn((float)gx * fs, 0.5f * fs);
      float acy = __fadd_rn((float)gy * fs, 0.5f * fs);
      float sx = sigmoidf_(tx), sy = sigmoidf_(ty);
      float cx = __fadd_rn(acx, __fmul_rn(__fsub_rn(sx, 0.5f), fs));
      float cy = __fadd_rn(acy, __fmul_rn(__fsub_rn(sy, 0.5f), fs));
      float wx = __fmul_rn(c_half[L][an][0], expf(tw));
      float wy = __fmul_rn(c_half[L][an][1], expf(th));
      bx.x = __fsub_rn(cx, wx); bx.y = __fsub_rn(cy, wy);
      bx.z = __fadd_rn(cx, wx); bx.w = __fadd_rn(cy, wy);
      contrib = fmaxf(fmaxf(bx.x, bx.y), fmaxf(bx.z, bx.w));
    }
    bs[i] = bx;
    lmax = fmaxf(lmax, contrib);
  }
  red[t] = lmax;
  for (int s = 512; s > 0; s >>= 1) {
    __syncthreads();
    if (t < s) red[t] = fmaxf(red[t], red[t + s]);
  }
  __syncthreads();
  if (t == 0) maxcv[b] = red[0];
}

// ---------------- K5: lazy greedy NMS, one wave per image --------------------------
__global__ void __launch_bounds__(64) k_nms(const u64* __restrict__ candKeys,
                                            const float4* __restrict__ boxS,
                                            const float* __restrict__ maxcv,
                                            float* __restrict__ out) {
  const int b = blockIdx.x;
  const int lane = threadIdx.x;
  float* dets = out + (size_t)b * (MAXDET * 5);
  float* lbls = out + (size_t)NIMG * MAXDET * 5 + (size_t)b * MAXDET;
  for (int i = lane; i < MAXDET; i += 64) {
    dets[i * 5 + 0] = 0.f; dets[i * 5 + 1] = 0.f; dets[i * 5 + 2] = 0.f;
    dets[i * 5 + 3] = 0.f; dets[i * 5 + 4] = 0.f;
    lbls[i] = -1.0f;
  }
  const float mc1 = __fadd_rn(maxcv[b], 1.0f);
  const u64* ck = candKeys + (size_t)b * TOPK;
  const float4* bs = boxS + (size_t)b * TOPK;
  float pbx1[2], pby1[2], pbx2[2], pby2[2], parea[2];
  int P = 0;
  bool done = false;
  for (int base = 0; base < TOPK && !done; base += 64) {
    const int e = base + lane;
    u64 key = ck[e];
    float score = -INFINITY; int c = 0;
    float4 bx = bs[e];
    if (key) {
      unsigned mb = (unsigned)(key >> 32);
      score = __uint_as_float(mb ^ 0x80000000u);
      unsigned idx = 0xFFFFFFFFu - (unsigned)(key & 0xFFFFFFFFull);
      c = (int)(idx % 80u);
    }
    float off = __fmul_rn((float)c, mc1);
    float nx1 = __fadd_rn(bx.x, off), ny1 = __fadd_rn(bx.y, off);
    float nx2 = __fadd_rn(bx.z, off), ny2 = __fadd_rn(bx.w, off);
    for (int tt = 0; tt < 64; ++tt) {
      float s_e = __shfl(score, tt);
      if (!(s_e > 0.0f)) { done = true; break; }
      float ex1 = __shfl(nx1, tt), ey1 = __shfl(ny1, tt);
      float ex2 = __shfl(nx2, tt), ey2 = __shfl(ny2, tt);
      float ea = __fmul_rn(__fsub_rn(ex2, ex1), __fsub_rn(ey2, ey1));
      bool sup = false;
      #pragma unroll
      for (int k2 = 0; k2 < 2; ++k2) {
        int pi = k2 * 64 + lane;
        if (pi < P) {
          float tlx = fmaxf(pbx1[k2], ex1), tly = fmaxf(pby1[k2], ey1);
          float brx = fminf(pbx2[k2], ex2), bry = fminf(pby2[k2], ey2);
          float iw = fmaxf(__fsub_rn(brx, tlx), 0.0f);
          float ih = fmaxf(__fsub_rn(bry, tly), 0.0f);
          float inter = __fmul_rn(iw, ih);
          float denom = __fadd_rn(__fsub_rn(__fadd_rn(parea[k2], ea), inter), 1e-12f);
          float iou = __fdiv_rn(inter, denom);
          if (iou > IOU_THR) sup = true;
        }
      }
      if (!__any(sup)) {
        float cx1 = __shfl(bx.x, tt), cy1 = __shfl(bx.y, tt);
        float cx2 = __shfl(bx.z, tt), cy2 = __shfl(bx.w, tt);
        int   ce  = __shfl(c, tt);
        if (lane == (P & 63)) {
          int slot = P >> 6;
          pbx1[slot] = ex1; pby1[slot] = ey1; pbx2[slot] = ex2; pby2[slot] = ey2;
          parea[slot] = ea;
        }
        if (lane == 0) {
          dets[P * 5 + 0] = cx1; dets[P * 5 + 1] = cy1;
          dets[P * 5 + 2] = cx2; dets[P * 5 + 3] = cy2;
          dets[P * 5 + 4] = s_e;
          lbls[P] = (float)ce;
        }
        ++P;
        if (P == MAXDET) { done = true; break; }
      }
    }
  }
}

// ---------------- launch -----------------------------------------------------------
extern "C" void kernel_launch(void* const* d_in, const int* in_sizes, int n_in,
                              void* d_out, int out_size, void* d_ws, size_t ws_size,
                              hipStream_t stream) {
  const float* p0 = (const float*)d_in[0];  // [16,255,19,19]
  const float* p1 = (const float*)d_in[1];  // [16,255,38,38]
  const float* p2 = (const float*)d_in[2];  // [16,255,76,76]
  float* out = (float*)d_out;
  char* ws = (char*)d_ws;

  const size_t OFF_MERGED = 0;                          // 16*8192*4  = 524288
  const size_t OFF_CNT    = 524288;                     // 256 B counters
  const size_t OFF_CK     = 524544;                     // 16*4096*8  = 524288
  const size_t OFF_BL     = 1048832;                    // 16*8192*8  = 1048576
  const size_t OFF_BOX    = 2097408;                    // 16*4096*16 = 1048576
  const size_t OFF_PRIV   = 3145984;                    // 768*8192*4 = 25165824
  const size_t NEED_PRIV  = OFF_PRIV + (size_t)NBLK_H * NHIST * 4;  // ~28.3 MB

  unsigned* merged = (unsigned*)(ws + OFF_MERGED);
  unsigned* candCount = (unsigned*)(ws + OFF_CNT);
  unsigned* bCount = candCount + 16;
  int* bb1 = (int*)(bCount + 16);
  float* maxcv = (float*)(bb1 + 16);
  u64* candKeys = (u64*)(ws + OFF_CK);
  u64* blist = (u64*)(ws + OFF_BL);
  float4* boxS = (float4*)(ws + OFF_BOX);
  unsigned* priv = (unsigned*)(ws + OFF_PRIV);

  const bool use_priv = ws_size >= NEED_PRIV;
  if (use_priv) {
    hipMemsetAsync(ws + OFF_CNT, 0, 256, stream);
    k_hist<true><<<NBLK_H, 128, 0, stream>>>(p0, p1, p2, priv);
    k_merge<<<dim3(NHIST / 256, NIMG), 256, 0, stream>>>(priv, merged);
  } else {
    hipMemsetAsync(ws, 0, OFF_CNT + 256, stream);
    k_hist<false><<<NBLK_H, 128, 0, stream>>>(p0, p1, p2, merged);
  }
  k_scan<<<NIMG, 256, 0, stream>>>(merged, bb1);
  k_collect<<<NBLK_C, 256, 0, stream>>>(p0, p1, p2, bb1, candCount, bCount, candKeys, blist);
  k_bsel<<<NIMG, 1024, 0, stream>>>(candCount, bCount, candKeys, blist);
  k_chunksort<<<NIMG * 4, 256, 0, stream>>>(candKeys);
  k_mergedecode<<<NIMG, 1024, 0, stream>>>(candKeys, p0, p1, p2, boxS, maxcv);
  k_nms<<<NIMG, 64, 0, stream>>>(candKeys, boxS, maxcv, out);
}